// Round 4
// baseline (72.209 us; speedup 1.0000x reference)
//
#include <hip/hip_runtime.h>
#include <math.h>

#define NPIX 512
#define NK 11            // low-frequency k = 0..10 (i+j <= 10 triangle fits in 11x11 corner)
#define NKP 12           // padded row length for the transposed table (48 B, 16B-aligned)
#define NPAIR 121        // 11*11 (invalid k+l>10 zeroed in the reduce)
#define RBLKS 8          // row-blocks per channel (64 rows each)
#define NCH 96           // 32*3 channels

// cos(2*pi*rev) via the hardware v_cos_f32 (input in revolutions).
#if __has_builtin(__builtin_amdgcn_cosf)
__device__ inline float cos_rev(float rev) { return __builtin_amdgcn_cosf(rev); }
#else
__device__ inline float cos_rev(float rev) { return __cosf(rev * 6.28318530717958647692f); }
#endif

// C[k][h] = 2*cos(pi*(2h+1)*k/1024) = 2*cos(2*pi*m/2048), m = (2h+1)*k mod 2048.
// m/2048 is exact in fp32; v_cos error (~1e-6) contributes ~1e-4 to the output
// (budget 0.108; fp32-accumulation floor is 0.0156).
__device__ inline float ctab(int h, int k) {
    int m = ((2 * h + 1) * k) & 2047;
    return 2.0f * cos_rev((float)m * (1.0f / 2048.0f));
}

// Build transposed table Cst[h][k] (k = 0..10, slot 11 zero) for broadcast
// ds_read_b128 access: 3 float4s cover all 11 k for one h.
__device__ inline void build_Cst(float (*Cst)[NKP], int t) {
    float* f = (float*)Cst;
#pragma unroll
    for (int i = t; i < NPIX * NKP; i += 256) {
        int h = i / NKP;
        int k = i - h * NKP;
        f[i] = (k < NK) ? ctab(h, k) : 0.f;
    }
}

// ---------------------------------------------------------------------------
// K1: per (channel, row-block) partial low-frequency coefficients.
//   a[k][j]   = sum_{h in 32-row half} C[k][h] * im[h][w0+j]   (registers)
//   pk[k](l)  = sum_j a[k][j] * C[l][w0+j]                      (registers)
//   16-lane shfl reduce -> red[16][121] -> block reduce -> plow[bid][k*11+l]
// ---------------------------------------------------------------------------
__global__ __launch_bounds__(256) void k_partial(const float* __restrict__ im,
                                                 float* __restrict__ plow) {
    __shared__ float Cst[NPIX][NKP];   // 24.0 KB
    __shared__ float red[16][NPAIR];   // 7.6 KB group-reduce buffer

    int bid = blockIdx.x;
    int c = bid >> 3, rb = bid & 7;
    int t = threadIdx.x;

    build_Cst(Cst, t);
    __syncthreads();

    int half = t >> 7;
    int col4 = t & 127;
    int w0 = col4 * 4;
    int rowbase = rb * 64 + half * 32;
    const float* imc = im + (size_t)c * NPIX * NPIX + (size_t)rowbase * NPIX + w0;

    float a[NK][4];
#pragma unroll
    for (int k = 0; k < NK; ++k)
        for (int j = 0; j < 4; ++j) a[k][j] = 0.f;

#pragma unroll 4
    for (int i = 0; i < 32; ++i) {
        int h = rowbase + i;
        float4 v = *(const float4*)(imc + (size_t)i * NPIX);
        const float4* crow = (const float4*)&Cst[h][0];
        float4 c0 = crow[0], c1 = crow[1], c2 = crow[2];  // broadcast b128 x3
        float ck[12];
        *(float4*)&ck[0] = c0; *(float4*)&ck[4] = c1; *(float4*)&ck[8] = c2;
#pragma unroll
        for (int k = 0; k < NK; ++k) {
            a[k][0] += ck[k] * v.x;
            a[k][1] += ck[k] * v.y;
            a[k][2] += ck[k] * v.z;
            a[k][3] += ck[k] * v.w;
        }
    }

    // Register contraction over this thread's 4 columns + 16-lane-group reduce.
#pragma unroll
    for (int l = 0; l < NK; ++l) {
        float cl0 = ctab(w0 + 0, l);
        float cl1 = ctab(w0 + 1, l);
        float cl2 = ctab(w0 + 2, l);
        float cl3 = ctab(w0 + 3, l);
        float pk[NK];
#pragma unroll
        for (int k = 0; k < NK; ++k)
            pk[k] = a[k][0] * cl0 + a[k][1] * cl1 + a[k][2] * cl2 + a[k][3] * cl3;
#pragma unroll
        for (int s = 1; s <= 8; s <<= 1)
#pragma unroll
            for (int k = 0; k < NK; ++k) pk[k] += __shfl_xor(pk[k], s);
        if ((t & 15) == 0)
#pragma unroll
            for (int k = 0; k < NK; ++k) red[t >> 4][k * NK + l] = pk[k];  // [k][l]!
    }
    __syncthreads();

    if (t < NPAIR) {
        float s = 0.f;
#pragma unroll
        for (int g = 0; g < 16; ++g) s += red[g][t];
        plow[(size_t)bid * NPAIR + t] = s;
    }
}

// ---------------------------------------------------------------------------
// K2: out = im - rank-66 correction (finalize fused in).
//   Ls[k][l] = s_k*s_l * sum_b plow[c][b][k*11+l], zeroed for k+l>10
//   B[k][j]  = sum_{l<=10-k} Ls[k][l] * C[l][w0+j]   (v_cos, registers)
//   corr     = sum_k C[k][h] * B[k][j]
// ---------------------------------------------------------------------------
__global__ __launch_bounds__(256) void k_output(const float* __restrict__ im,
                                                const float* __restrict__ plow,
                                                float* __restrict__ out) {
    __shared__ float Cst[NPIX][NKP];
    __shared__ float Ls[NPAIR];

    int bid = blockIdx.x;
    int c = bid >> 3, rb = bid & 7;
    int t = threadIdx.x;

    build_Cst(Cst, t);

    if (t < NPAIR) {
        int k = t / NK, l = t % NK;
        float s = 0.f;
        const float* pp = plow + (size_t)c * RBLKS * NPAIR + t;
#pragma unroll
        for (int b = 0; b < RBLKS; ++b) s += pp[b * NPAIR];
        float sk = (k == 0 ? 0.5f : 1.0f) * (1.0f / 1024.0f);
        float sl = (l == 0 ? 0.5f : 1.0f) * (1.0f / 1024.0f);
        Ls[t] = (k + l <= 10) ? s * sk * sl : 0.f;
    }
    __syncthreads();

    int half = t >> 7;
    int col4 = t & 127;
    int w0 = col4 * 4;
    int rowbase = rb * 64 + half * 32;

    // B[k][j] for this thread's 4 columns (Ls broadcast, C via v_cos).
    // Only the k+l<=10 triangle is nonzero -> 66 terms.
    float B[NK][4];
#pragma unroll
    for (int k = 0; k < NK; ++k)
        for (int j = 0; j < 4; ++j) B[k][j] = 0.f;

#pragma unroll
    for (int l = 0; l < NK; ++l) {
        float cl0 = ctab(w0 + 0, l);
        float cl1 = ctab(w0 + 1, l);
        float cl2 = ctab(w0 + 2, l);
        float cl3 = ctab(w0 + 3, l);
#pragma unroll
        for (int k = 0; k < NK; ++k) {
            if (k + l > 10) break;
            float lw = Ls[k * NK + l];  // broadcast
            B[k][0] += lw * cl0;
            B[k][1] += lw * cl1;
            B[k][2] += lw * cl2;
            B[k][3] += lw * cl3;
        }
    }

    const float* imc = im + (size_t)c * NPIX * NPIX + (size_t)rowbase * NPIX + w0;
    float* outc = out + (size_t)c * NPIX * NPIX + (size_t)rowbase * NPIX + w0;

#pragma unroll 4
    for (int i = 0; i < 32; ++i) {
        int h = rowbase + i;
        float4 v = *(const float4*)(imc + (size_t)i * NPIX);
        const float4* crow = (const float4*)&Cst[h][0];
        float4 c0 = crow[0], c1 = crow[1], c2 = crow[2];  // broadcast b128 x3
        float ck[12];
        *(float4*)&ck[0] = c0; *(float4*)&ck[4] = c1; *(float4*)&ck[8] = c2;
        float r0 = 0.f, r1 = 0.f, r2 = 0.f, r3 = 0.f;
#pragma unroll
        for (int k = 0; k < NK; ++k) {
            r0 += ck[k] * B[k][0];
            r1 += ck[k] * B[k][1];
            r2 += ck[k] * B[k][2];
            r3 += ck[k] * B[k][3];
        }
        float4 o = make_float4(v.x - r0, v.y - r1, v.z - r2, v.w - r3);
        *(float4*)(outc + (size_t)i * NPIX) = o;
    }
}

// ---------------------------------------------------------------------------
// Launch: im (32,3,512,512) f32 -> out same shape.
// ws layout (floats): [plow: 96*8*121] ~ 372 KB
// ---------------------------------------------------------------------------
extern "C" void kernel_launch(void* const* d_in, const int* in_sizes, int n_in,
                              void* d_out, int out_size, void* d_ws, size_t ws_size,
                              hipStream_t stream) {
    const float* im = (const float*)d_in[0];
    float* out = (float*)d_out;
    float* plow = (float*)d_ws;  // NCH*RBLKS*NPAIR floats

    k_partial<<<NCH * RBLKS, 256, 0, stream>>>(im, plow);
    k_output<<<NCH * RBLKS, 256, 0, stream>>>(im, plow, out);
}

// Round 5
// 69.383 us; speedup vs baseline: 1.0407x; 1.0407x over previous
//
#include <hip/hip_runtime.h>
#include <math.h>

#define NPIX 512
#define NK 11            // low-frequency k = 0..10 (i+j <= 10 triangle fits in 11x11 corner)
#define NKP 12           // padded table row (48 B, 16B-aligned)
#define NPAIR 121        // 11*11 (invalid k+l>10 zeroed in the reduce)
#define RBLKS 8          // row-blocks per channel (64 rows each)
#define NCH 96           // 32*3 channels

// cos(2*pi*rev) via the hardware v_cos_f32 (input in revolutions).
#if __has_builtin(__builtin_amdgcn_cosf)
__device__ inline float cos_rev(float rev) { return __builtin_amdgcn_cosf(rev); }
#else
__device__ inline float cos_rev(float rev) { return __cosf(rev * 6.28318530717958647692f); }
#endif

// C[k][h] = 2*cos(pi*(2h+1)*k/1024) = 2*cos(2*pi*m/2048), m = (2h+1)*k mod 2048.
// m/2048 exact in fp32; v_cos error ~1e-6 -> ~1e-4 in output (budget 0.108).
__device__ inline float ctab(int h, int k) {
    int m = ((2 * h + 1) * k) & 2047;
    return 2.0f * cos_rev((float)m * (1.0f / 2048.0f));
}

// 16-lane full sum via DPP row rotates (VALU pipe — keeps the LDS pipe free).
#if __has_builtin(__builtin_amdgcn_update_dpp)
template <int CTRL>
__device__ inline float dpp_add(float x) {
    int xi = __builtin_bit_cast(int, x);
    int yi = __builtin_amdgcn_update_dpp(0, xi, CTRL, 0xf, 0xf, false);
    return x + __builtin_bit_cast(float, yi);
}
__device__ inline float red16(float x) {
    x = dpp_add<0x128>(x);  // row_ror:8
    x = dpp_add<0x124>(x);  // row_ror:4
    x = dpp_add<0x122>(x);  // row_ror:2
    x = dpp_add<0x121>(x);  // row_ror:1
    return x;
}
#else
__device__ inline float red16(float x) {
    x += __shfl_xor(x, 8);
    x += __shfl_xor(x, 4);
    x += __shfl_xor(x, 2);
    x += __shfl_xor(x, 1);
    return x;
}
#endif

// Build the block's 64-row transposed table Cs64[hl][k], k slot 11 zeroed.
__device__ inline void build_Cs64(float (*Cs64)[NKP], int t, int row0) {
#pragma unroll
    for (int j = 0; j < 3; ++j) {
        int idx = j * 256 + t;  // 768 = 64*12 entries
        int hl = idx / NKP;
        int kk = idx - hl * NKP;
        Cs64[hl][kk] = (kk < NK) ? ctab(row0 + hl, kk) : 0.f;
    }
}

// All-k macro expansion (no addressable locals anywhere).
#define FMA4(ACC, CC) ACC.x += (CC) * v.x; ACC.y += (CC) * v.y; ACC.z += (CC) * v.z; ACC.w += (CC) * v.w;
#define DOT4(ACC) ((ACC).x * cl0 + (ACC).y * cl1 + (ACC).z * cl2 + (ACC).w * cl3)

// ---------------------------------------------------------------------------
// K1: per (channel, row-block) partial low-frequency coefficients.
//   acc_k (float4) = sum_h C[k][h] * im[h][w0..w0+3]       (pure registers)
//   p_k(l) = dot(acc_k, C[l][w0..w0+3])  -> DPP 16-lane reduce -> LDS combine
// ---------------------------------------------------------------------------
__global__ __launch_bounds__(256, 4) void k_partial(const float* __restrict__ im,
                                                    float* __restrict__ plow) {
    __shared__ float Cs64[64][NKP];    // 3.0 KB: this block's rows only
    __shared__ float red[16][NPAIR];   // 7.6 KB group-reduce buffer

    int bid = blockIdx.x;
    int c = bid >> 3, rb = bid & 7;
    int t = threadIdx.x;
    int row0 = rb * 64;

    build_Cs64(Cs64, t, row0);
    __syncthreads();

    int half = t >> 7;
    int col4 = t & 127;
    int w0 = col4 * 4;
    int hbase = half * 32;
    const float* imc = im + (size_t)c * NPIX * NPIX + (size_t)(row0 + hbase) * NPIX + w0;

    float4 z = make_float4(0.f, 0.f, 0.f, 0.f);
    float4 a0 = z, a1 = z, a2 = z, a3 = z, a4 = z, a5 = z, a6 = z, a7 = z, a8 = z, a9 = z, a10 = z;

#pragma unroll 4
    for (int i = 0; i < 32; ++i) {
        float4 v = *(const float4*)(imc + (size_t)i * NPIX);
        const float4* crow = (const float4*)&Cs64[hbase + i][0];
        float4 c0 = crow[0], c1 = crow[1], c2 = crow[2];  // broadcast b128 x3
        FMA4(a0, c0.x) FMA4(a1, c0.y) FMA4(a2, c0.z) FMA4(a3, c0.w)
        FMA4(a4, c1.x) FMA4(a5, c1.y) FMA4(a6, c1.z) FMA4(a7, c1.w)
        FMA4(a8, c2.x) FMA4(a9, c2.y) FMA4(a10, c2.z)
    }

    // Register contraction over this thread's 4 columns, DPP reduce over the
    // 16-lane group (64 columns), then one LDS combine across 16 groups.
    int g = t >> 4;
    for (int l = 0; l < NK; ++l) {
        float cl0 = ctab(w0 + 0, l);
        float cl1 = ctab(w0 + 1, l);
        float cl2 = ctab(w0 + 2, l);
        float cl3 = ctab(w0 + 3, l);
        float p0 = red16(DOT4(a0));
        float p1 = red16(DOT4(a1));
        float p2 = red16(DOT4(a2));
        float p3 = red16(DOT4(a3));
        float p4 = red16(DOT4(a4));
        float p5 = red16(DOT4(a5));
        float p6 = red16(DOT4(a6));
        float p7 = red16(DOT4(a7));
        float p8 = red16(DOT4(a8));
        float p9 = red16(DOT4(a9));
        float p10 = red16(DOT4(a10));
        if ((t & 15) == 0) {
            red[g][0 * NK + l] = p0;  red[g][1 * NK + l] = p1;  red[g][2 * NK + l] = p2;
            red[g][3 * NK + l] = p3;  red[g][4 * NK + l] = p4;  red[g][5 * NK + l] = p5;
            red[g][6 * NK + l] = p6;  red[g][7 * NK + l] = p7;  red[g][8 * NK + l] = p8;
            red[g][9 * NK + l] = p9;  red[g][10 * NK + l] = p10;
        }
    }
    __syncthreads();

    if (t < NPAIR) {
        float s = 0.f;
#pragma unroll
        for (int gg = 0; gg < 16; ++gg) s += red[gg][t];
        plow[(size_t)bid * NPAIR + t] = s;   // [k][l] order
    }
}

// ---------------------------------------------------------------------------
// K2: out = im - rank-66 correction (finalize fused in).
//   Ls[k][l] = s_k*s_l * sum_b plow[c][b][k*11+l], zeroed for k+l>10
//   B_k (float4) = sum_l Ls[k][l] * C[l][w0..w0+3]   (v_cos, registers)
//   out = im - sum_k C[k][h] * B_k
// ---------------------------------------------------------------------------
__global__ __launch_bounds__(256, 4) void k_output(const float* __restrict__ im,
                                                   const float* __restrict__ plow,
                                                   float* __restrict__ out) {
    __shared__ float Cs64[64][NKP];
    __shared__ float Ls[NPAIR];

    int bid = blockIdx.x;
    int c = bid >> 3, rb = bid & 7;
    int t = threadIdx.x;
    int row0 = rb * 64;

    build_Cs64(Cs64, t, row0);

    if (t < NPAIR) {
        int k = t / NK, l = t % NK;
        float s = 0.f;
        const float* pp = plow + (size_t)c * RBLKS * NPAIR + t;
#pragma unroll
        for (int b = 0; b < RBLKS; ++b) s += pp[b * NPAIR];
        float sk = (k == 0 ? 0.5f : 1.0f) * (1.0f / 1024.0f);
        float sl = (l == 0 ? 0.5f : 1.0f) * (1.0f / 1024.0f);
        Ls[t] = (k + l <= 10) ? s * sk * sl : 0.f;  // triangle zeroed here
    }
    __syncthreads();

    int half = t >> 7;
    int col4 = t & 127;
    int w0 = col4 * 4;
    int hbase = half * 32;

    float4 z = make_float4(0.f, 0.f, 0.f, 0.f);
    float4 B0 = z, B1 = z, B2 = z, B3 = z, B4 = z, B5 = z, B6 = z, B7 = z, B8 = z, B9 = z, B10 = z;

#define BADD(BK, KI) { float lw = Ls[(KI) * NK + l]; BK.x += lw * cl0; BK.y += lw * cl1; BK.z += lw * cl2; BK.w += lw * cl3; }
    for (int l = 0; l < NK; ++l) {
        float cl0 = ctab(w0 + 0, l);
        float cl1 = ctab(w0 + 1, l);
        float cl2 = ctab(w0 + 2, l);
        float cl3 = ctab(w0 + 3, l);
        BADD(B0, 0) BADD(B1, 1) BADD(B2, 2) BADD(B3, 3) BADD(B4, 4) BADD(B5, 5)
        BADD(B6, 6) BADD(B7, 7) BADD(B8, 8) BADD(B9, 9) BADD(B10, 10)
    }

    const float* imc = im + (size_t)c * NPIX * NPIX + (size_t)(row0 + hbase) * NPIX + w0;
    float* outc = out + (size_t)c * NPIX * NPIX + (size_t)(row0 + hbase) * NPIX + w0;

#define CORR(comp) (c0.x * B0.comp + c0.y * B1.comp + c0.z * B2.comp + c0.w * B3.comp \
                  + c1.x * B4.comp + c1.y * B5.comp + c1.z * B6.comp + c1.w * B7.comp \
                  + c2.x * B8.comp + c2.y * B9.comp + c2.z * B10.comp)

#pragma unroll 4
    for (int i = 0; i < 32; ++i) {
        float4 v = *(const float4*)(imc + (size_t)i * NPIX);
        const float4* crow = (const float4*)&Cs64[hbase + i][0];
        float4 c0 = crow[0], c1 = crow[1], c2 = crow[2];  // broadcast b128 x3
        float4 o = make_float4(v.x - CORR(x), v.y - CORR(y), v.z - CORR(z), v.w - CORR(w));
        *(float4*)(outc + (size_t)i * NPIX) = o;
    }
}

// ---------------------------------------------------------------------------
// Launch: im (32,3,512,512) f32 -> out same shape.
// ws layout (floats): [plow: 96*8*121] ~ 372 KB
// ---------------------------------------------------------------------------
extern "C" void kernel_launch(void* const* d_in, const int* in_sizes, int n_in,
                              void* d_out, int out_size, void* d_ws, size_t ws_size,
                              hipStream_t stream) {
    const float* im = (const float*)d_in[0];
    float* out = (float*)d_out;
    float* plow = (float*)d_ws;  // NCH*RBLKS*NPAIR floats

    k_partial<<<NCH * RBLKS, 256, 0, stream>>>(im, plow);
    k_output<<<NCH * RBLKS, 256, 0, stream>>>(im, plow, out);
}

// Round 7
// 61.054 us; speedup vs baseline: 1.1827x; 1.1364x over previous
//
#include <hip/hip_runtime.h>
#include <math.h>

#define NPIX 512
#define NK 11            // low-frequency k = 0..10 (i+j <= 10 triangle fits in 11x11 corner)
#define NKP 12           // padded table row (48 B, 16B-aligned)
#define NPAIR 121        // 11*11 (invalid k+l>10 zeroed in the reduce)
#define RBLKS 8          // row-blocks per channel (64 rows each)
#define NCH 96           // 32*3 channels

// Native clang vector for nontemporal stores (HIP float4 is a class type,
// which __builtin_nontemporal_store rejects).
typedef float vfloat4 __attribute__((ext_vector_type(4)));

// cos(2*pi*rev) via the hardware v_cos_f32 (input in revolutions).
#if __has_builtin(__builtin_amdgcn_cosf)
__device__ inline float cos_rev(float rev) { return __builtin_amdgcn_cosf(rev); }
#else
__device__ inline float cos_rev(float rev) { return __cosf(rev * 6.28318530717958647692f); }
#endif

// C[k][h] = 2*cos(pi*(2h+1)*k/1024) = 2*cos(2*pi*m/2048), m = (2h+1)*k mod 2048.
// m/2048 exact in fp32; v_cos error ~1e-6 -> ~1e-4 in output (budget 0.108).
__device__ inline float ctab(int h, int k) {
    int m = ((2 * h + 1) * k) & 2047;
    return 2.0f * cos_rev((float)m * (1.0f / 2048.0f));
}

// 16-lane full sum via DPP row rotates (VALU pipe — keeps the LDS pipe free).
#if __has_builtin(__builtin_amdgcn_update_dpp)
template <int CTRL>
__device__ inline float dpp_add(float x) {
    int xi = __builtin_bit_cast(int, x);
    int yi = __builtin_amdgcn_update_dpp(0, xi, CTRL, 0xf, 0xf, false);
    return x + __builtin_bit_cast(float, yi);
}
__device__ inline float red16(float x) {
    x = dpp_add<0x128>(x);  // row_ror:8
    x = dpp_add<0x124>(x);  // row_ror:4
    x = dpp_add<0x122>(x);  // row_ror:2
    x = dpp_add<0x121>(x);  // row_ror:1
    return x;
}
#else
__device__ inline float red16(float x) {
    x += __shfl_xor(x, 8);
    x += __shfl_xor(x, 4);
    x += __shfl_xor(x, 2);
    x += __shfl_xor(x, 1);
    return x;
}
#endif

// Build the block's 64-row transposed table Cs64[hl][k], k slot 11 zeroed.
__device__ inline void build_Cs64(float (*Cs64)[NKP], int t, int row0) {
#pragma unroll
    for (int j = 0; j < 3; ++j) {
        int idx = j * 256 + t;  // 768 = 64*12 entries
        int hl = idx / NKP;
        int kk = idx - hl * NKP;
        Cs64[hl][kk] = (kk < NK) ? ctab(row0 + hl, kk) : 0.f;
    }
}

// All-k macro expansion (no addressable locals anywhere).
#define FMA4(ACC, CC) ACC.x += (CC) * v.x; ACC.y += (CC) * v.y; ACC.z += (CC) * v.z; ACC.w += (CC) * v.w;
#define DOT4(ACC) ((ACC).x * cl0 + (ACC).y * cl1 + (ACC).z * cl2 + (ACC).w * cl3)

// ---------------------------------------------------------------------------
// K1: per (channel, row-block) partial low-frequency coefficients.
//   acc_k (float4) = sum_h C[k][h] * im[h][w0..w0+3]       (pure registers)
//   p_k(l) = dot(acc_k, C[l][w0..w0+3])  -> DPP 16-lane reduce -> LDS combine
// ---------------------------------------------------------------------------
__global__ __launch_bounds__(256, 4) void k_partial(const float* __restrict__ im,
                                                    float* __restrict__ plow) {
    __shared__ float Cs64[64][NKP];    // 3.0 KB: this block's rows only
    __shared__ float red[16][NPAIR];   // 7.6 KB group-reduce buffer

    int bid = blockIdx.x;
    int c = bid >> 3, rb = bid & 7;
    int t = threadIdx.x;
    int row0 = rb * 64;

    build_Cs64(Cs64, t, row0);
    __syncthreads();

    int half = t >> 7;
    int col4 = t & 127;
    int w0 = col4 * 4;
    int hbase = half * 32;
    const float* imc = im + (size_t)c * NPIX * NPIX + (size_t)(row0 + hbase) * NPIX + w0;

    float4 z = make_float4(0.f, 0.f, 0.f, 0.f);
    float4 a0 = z, a1 = z, a2 = z, a3 = z, a4 = z, a5 = z, a6 = z, a7 = z, a8 = z, a9 = z, a10 = z;

#pragma unroll 4
    for (int i = 0; i < 32; ++i) {
        float4 v = *(const float4*)(imc + (size_t)i * NPIX);
        const float4* crow = (const float4*)&Cs64[hbase + i][0];
        float4 c0 = crow[0], c1 = crow[1], c2 = crow[2];  // broadcast b128 x3
        FMA4(a0, c0.x) FMA4(a1, c0.y) FMA4(a2, c0.z) FMA4(a3, c0.w)
        FMA4(a4, c1.x) FMA4(a5, c1.y) FMA4(a6, c1.z) FMA4(a7, c1.w)
        FMA4(a8, c2.x) FMA4(a9, c2.y) FMA4(a10, c2.z)
    }

    // Register contraction over this thread's 4 columns, DPP reduce over the
    // 16-lane group (64 columns), then one LDS combine across 16 groups.
    int g = t >> 4;
    for (int l = 0; l < NK; ++l) {
        float cl0 = ctab(w0 + 0, l);
        float cl1 = ctab(w0 + 1, l);
        float cl2 = ctab(w0 + 2, l);
        float cl3 = ctab(w0 + 3, l);
        float p0 = red16(DOT4(a0));
        float p1 = red16(DOT4(a1));
        float p2 = red16(DOT4(a2));
        float p3 = red16(DOT4(a3));
        float p4 = red16(DOT4(a4));
        float p5 = red16(DOT4(a5));
        float p6 = red16(DOT4(a6));
        float p7 = red16(DOT4(a7));
        float p8 = red16(DOT4(a8));
        float p9 = red16(DOT4(a9));
        float p10 = red16(DOT4(a10));
        if ((t & 15) == 0) {
            red[g][0 * NK + l] = p0;  red[g][1 * NK + l] = p1;  red[g][2 * NK + l] = p2;
            red[g][3 * NK + l] = p3;  red[g][4 * NK + l] = p4;  red[g][5 * NK + l] = p5;
            red[g][6 * NK + l] = p6;  red[g][7 * NK + l] = p7;  red[g][8 * NK + l] = p8;
            red[g][9 * NK + l] = p9;  red[g][10 * NK + l] = p10;
        }
    }
    __syncthreads();

    if (t < NPAIR) {
        float s = 0.f;
#pragma unroll
        for (int gg = 0; gg < 16; ++gg) s += red[gg][t];
        plow[(size_t)bid * NPAIR + t] = s;   // [k][l] order
    }
}

// ---------------------------------------------------------------------------
// K2: out = im - rank-66 correction (finalize fused in).
//   Ls[k][l] = s_k*s_l * sum_b plow[c][b][k*11+l], zeroed for k+l>10
//   B_k (float4) = sum_l Ls[k][l] * C[l][w0..w0+3]   (v_cos, registers)
//   out = im - sum_k C[k][h] * B_k            (NONTEMPORAL stores)
// ---------------------------------------------------------------------------
__global__ __launch_bounds__(256, 2) void k_output(const float* __restrict__ im,
                                                   const float* __restrict__ plow,
                                                   float* __restrict__ out) {
    __shared__ float Cs64[64][NKP];
    __shared__ float Ls[NPAIR];

    int bid = blockIdx.x;
    int c = bid >> 3, rb = bid & 7;
    int t = threadIdx.x;
    int row0 = rb * 64;

    build_Cs64(Cs64, t, row0);

    if (t < NPAIR) {
        int k = t / NK, l = t % NK;
        float s = 0.f;
        const float* pp = plow + (size_t)c * RBLKS * NPAIR + t;
#pragma unroll
        for (int b = 0; b < RBLKS; ++b) s += pp[b * NPAIR];
        float sk = (k == 0 ? 0.5f : 1.0f) * (1.0f / 1024.0f);
        float sl = (l == 0 ? 0.5f : 1.0f) * (1.0f / 1024.0f);
        Ls[t] = (k + l <= 10) ? s * sk * sl : 0.f;  // triangle zeroed here
    }
    __syncthreads();

    int half = t >> 7;
    int col4 = t & 127;
    int w0 = col4 * 4;
    int hbase = half * 32;

    float4 z = make_float4(0.f, 0.f, 0.f, 0.f);
    float4 B0 = z, B1 = z, B2 = z, B3 = z, B4 = z, B5 = z, B6 = z, B7 = z, B8 = z, B9 = z, B10 = z;

#define BADD(BK, KI) { float lw = Ls[(KI) * NK + l]; BK.x += lw * cl0; BK.y += lw * cl1; BK.z += lw * cl2; BK.w += lw * cl3; }
    for (int l = 0; l < NK; ++l) {
        float cl0 = ctab(w0 + 0, l);
        float cl1 = ctab(w0 + 1, l);
        float cl2 = ctab(w0 + 2, l);
        float cl3 = ctab(w0 + 3, l);
        BADD(B0, 0) BADD(B1, 1) BADD(B2, 2) BADD(B3, 3) BADD(B4, 4) BADD(B5, 5)
        BADD(B6, 6) BADD(B7, 7) BADD(B8, 8) BADD(B9, 9) BADD(B10, 10)
    }

    const float* imc = im + (size_t)c * NPIX * NPIX + (size_t)(row0 + hbase) * NPIX + w0;
    float* outc = out + (size_t)c * NPIX * NPIX + (size_t)(row0 + hbase) * NPIX + w0;

#define CORR(comp) (c0.x * B0.comp + c0.y * B1.comp + c0.z * B2.comp + c0.w * B3.comp \
                  + c1.x * B4.comp + c1.y * B5.comp + c1.z * B6.comp + c1.w * B7.comp \
                  + c2.x * B8.comp + c2.y * B9.comp + c2.z * B10.comp)

#pragma unroll 4
    for (int i = 0; i < 32; ++i) {
        float4 v = *(const float4*)(imc + (size_t)i * NPIX);
        const float4* crow = (const float4*)&Cs64[hbase + i][0];
        float4 c0 = crow[0], c1 = crow[1], c2 = crow[2];  // broadcast b128 x3
        vfloat4 o;
        o.x = v.x - CORR(x);
        o.y = v.y - CORR(y);
        o.z = v.z - CORR(z);
        o.w = v.w - CORR(w);
#if __has_builtin(__builtin_nontemporal_store)
        __builtin_nontemporal_store(o, (vfloat4*)(outc + (size_t)i * NPIX));
#else
        *(vfloat4*)(outc + (size_t)i * NPIX) = o;
#endif
    }
}

// ---------------------------------------------------------------------------
// Launch: im (32,3,512,512) f32 -> out same shape.
// ws layout (floats): [plow: 96*8*121] ~ 372 KB
// ---------------------------------------------------------------------------
extern "C" void kernel_launch(void* const* d_in, const int* in_sizes, int n_in,
                              void* d_out, int out_size, void* d_ws, size_t ws_size,
                              hipStream_t stream) {
    const float* im = (const float*)d_in[0];
    float* out = (float*)d_out;
    float* plow = (float*)d_ws;  // NCH*RBLKS*NPAIR floats

    k_partial<<<NCH * RBLKS, 256, 0, stream>>>(im, plow);
    k_output<<<NCH * RBLKS, 256, 0, stream>>>(im, plow, out);
}